// Round 2
// 64.303 us; speedup vs baseline: 1.0174x; 1.0174x over previous
//
#include <hip/hip_runtime.h>

#ifndef __has_builtin
#define __has_builtin(x) 0
#endif

__device__ __forceinline__ float fast_exp2(float x) {
#if __has_builtin(__builtin_amdgcn_exp2f)
  return __builtin_amdgcn_exp2f(x);
#else
  return exp2f(x);
#endif
}
__device__ __forceinline__ float fast_rcp(float x) {
#if __has_builtin(__builtin_amdgcn_rcpf)
  return __builtin_amdgcn_rcpf(x);
#else
  return 1.0f / x;
#endif
}

#define NG     512
#define NSEG   8
#define SEGLEN 64
#define PXB    64           // pixels per block (1 per lane), grid = 1024 blocks
#define QCUT   -21.0f       // exp2 exponent cutoff: alpha < 2^-21 skipped

// Fully per-wave pipeline: wave s preprocesses its own 64 gaussians in
// registers (no staging LDS, no barrier), culls against this block's row
// + 64-px window, and compacts survivors {mx,ka,B,cc}+{r,g,b} into ordered
// LDS slots via prefix-popcount. Main loop is then a plain counted loop over
// consecutive broadcast LDS reads (pipelinable). One block-wide barrier total
// (before the 8-segment associative combine).
// LDS 24.75 KB -> 4 blocks/CU -> 32 waves/CU (100% occupancy) with VGPR<=64.
__global__ __launch_bounds__(512, 8) void render_kernel(
    const float* __restrict__ means, const float* __restrict__ cov,
    const float* __restrict__ opac,  const float* __restrict__ cols,
    float* __restrict__ out)
{
  __shared__ float4 srow[NSEG][SEGLEN];   // 8 KB compacted {mx, ka, B, cc}
  __shared__ float4 scol[NSEG][SEGLEN];   // 8 KB compacted {r, g, b, -}
  __shared__ float4 part[NSEG][PXB];      // 8 KB per-segment per-pixel partials
  __shared__ float  outstage[PXB * 3];    // 768 B staged coalesced store

  const int tid  = threadIdx.x;
  const int lane = tid & 63;
  const int seg  = tid >> 6;
  const int pixbase = blockIdx.x * PXB;
  const float py  = (float)(pixbase >> 8) + 0.5f;   // block-constant row
  const float x0f = (float)(pixbase & 255) + 0.5f;  // x of local pixel 0
  const float px0 = x0f + (float)lane;              // lane's pixel x

  // ---- per-wave preprocess + row-fold + cull + compaction (no barrier) ----
  // alpha = exp2(ka*dx^2 + B*dx + cc) with B = kb*dy, cc = kc*dy^2 + ko.
  // q(dx) concave (ka<0): max at clamp(-B/(2ka), lo, hi); cull if q <= QCUT.
  int n;
  {
    const int g = seg * SEGLEN + lane;
    const float2 mu = ((const float2*)means)[g];
    const float4 cv = ((const float4*)cov)[g];      // {a, b, c, d}
    const float  op = opac[g];
    const float  c0 = cols[3*g+0], c1 = cols[3*g+1], c2 = cols[3*g+2];
    const float inv = fast_rcp(fmaf(cv.x, cv.w, -cv.y * cv.z)); // det >= 0.09
    const float HL2E = 0.72134752f;                 // 0.5*log2(e)
    const float ka = -HL2E * cv.w * inv;
    const float kb =  HL2E * (cv.y + cv.z) * inv;
    const float kc = -HL2E * cv.x * inv;
    const float ko = log2f(op);                     // opac in (0,1)
    const float dy = py - mu.y;
    const float Bv = kb * dy;
    const float cc = fmaf(kc * dy, dy, ko);
    const float lo = x0f - mu.x;
    const float hi = lo + (float)(PXB - 1);
    float dxs = Bv * (-0.5f * fast_rcp(ka));
    dxs = fminf(fmaxf(dxs, lo), hi);
    const float q = fmaf(fmaf(ka, dxs, Bv), dxs, cc);
    const bool live = (q > QCUT);
    const unsigned long long mask = __ballot(live);
    n = __popcll(mask);
    if (live) {
      const int ci = __popcll(mask & ((1ull << lane) - 1ull)); // order-preserving
      srow[seg][ci] = make_float4(mu.x, ka, Bv, cc);
      scol[seg][ci] = make_float4(c0, c1, c2, 0.f);
    }
    // same-wave LDS RAW below: hardware DS ops are in-order within a wave;
    // compiler inserts lgkmcnt before dependent reads of the same arrays.
  }

  // ---- main loop: compacted survivors, ascending order, SGPR trip count ----
  float T = 1.f, R = 0.f, G = 0.f, B = 0.f;
#pragma unroll 2
  for (int i = 0; i < n; ++i) {
    const float4 P = srow[seg][i];                  // wave-uniform -> broadcast
    const float4 C = scol[seg][i];
    const float dx = px0 - P.x;
    const float m  = fmaf(fmaf(P.y, dx, P.z), dx, P.w);
    const float a  = fast_exp2(m);
    const float aw = a * T;
    R = fmaf(aw, C.x, R);
    G = fmaf(aw, C.y, G);
    B = fmaf(aw, C.z, B);
    T *= (1.0000001f - a);                          // (1 - alpha + 1e-7)
  }

  part[seg][lane] = make_float4(R, G, B, T);
  __syncthreads();                                  // the only barrier

  // ---- epilogue: one wave combines 8 segment partials, stages, stores ----
  if (tid < PXB) {
    float Tt = 1.f, Rr = 0.f, Gg = 0.f, Bb = 0.f;
#pragma unroll
    for (int s = 0; s < NSEG; ++s) {
      const float4 p = part[s][tid];
      Rr = fmaf(Tt, p.x, Rr);
      Gg = fmaf(Tt, p.y, Gg);
      Bb = fmaf(Tt, p.z, Bb);
      Tt *= p.w;
    }
    outstage[tid*3+0] = Rr;
    outstage[tid*3+1] = Gg;
    outstage[tid*3+2] = Bb;
    __threadfence_block();                          // order same-wave LDS RAW
    // coalesced fp32 store: 192 contiguous floats per block
    out[pixbase*3 +       tid] = outstage[      tid];
    out[pixbase*3 +  64 + tid] = outstage[ 64 + tid];
    out[pixbase*3 + 128 + tid] = outstage[128 + tid];
  }
}

extern "C" void kernel_launch(void* const* d_in, const int* in_sizes, int n_in,
                              void* d_out, int out_size, void* d_ws, size_t ws_size,
                              hipStream_t stream) {
  const float* means = (const float*)d_in[0];   // (512,2)
  const float* cov   = (const float*)d_in[1];   // (512,2,2)
  const float* opac  = (const float*)d_in[2];   // (512,)
  const float* cols  = (const float*)d_in[3];   // (512,3)
  float* out = (float*)d_out;                   // (256,256,3) float32
  (void)in_sizes; (void)n_in; (void)out_size; (void)d_ws; (void)ws_size;
  render_kernel<<<dim3(256 * 256 / PXB), dim3(512), 0, stream>>>(
      means, cov, opac, cols, out);
}